// Round 1
// baseline (109.223 us; speedup 1.0000x reference)
//
#include <hip/hip_runtime.h>

#define MT 64
#define PADF 260  // floats per LDS row: 260*4B = 1040B, 16B-aligned, bank-skew 4

__global__ __launch_bounds__(256, 1) void tq_kernel(
    const float* __restrict__ X, const float* __restrict__ R,
    const float* __restrict__ CB, float* __restrict__ OUT) {
  __shared__ float xs[MT][PADF];
  __shared__ float rs[MT][PADF];
  __shared__ unsigned char ys[MT][256];
  __shared__ float pn[4][MT];
  __shared__ float s1[MT];
  __shared__ float s2[MT];
  __shared__ float cbs[16];

  const int tid = threadIdx.x;
  const int tx = tid & 15;
  const int ty = tid >> 4;
  const long row0 = (long)blockIdx.x * MT;

  // ---- stage x tile (coalesced float4) ----
  #pragma unroll
  for (int it = 0; it < 16; ++it) {
    int f = it * 256 + tid;   // float4 id within tile
    int i = f >> 6;           // row
    int c4 = f & 63;          // float4 within row
    float4 v = ((const float4*)(X + (row0 + i) * 256))[c4];
    *(float4*)&xs[i][c4 * 4] = v;
  }
  if (tid < 16) cbs[tid] = CB[tid];
  __syncthreads();

  // ---- row norms (4 threads per row) ----
  {
    int r = tid >> 2, q = tid & 3;
    float s = 0.f;
    #pragma unroll
    for (int j = 0; j < 64; j += 4) {
      float4 v = *(const float4*)&xs[r][q * 64 + j];
      s += v.x * v.x + v.y * v.y + v.z * v.z + v.w * v.w;
    }
    pn[q][r] = s;
  }
  // midpoints into registers (cbs was written before first sync)
  float mid[15];
  #pragma unroll
  for (int t = 0; t < 15; ++t) mid[t] = 0.5f * (cbs[t] + cbs[t + 1]);
  __syncthreads();
  if (tid < MT) {
    float s = pn[0][tid] + pn[1][tid] + pn[2][tid] + pn[3][tid];
    float nrm = fmaxf(sqrtf(s), 1e-8f);
    s1[tid] = 16.0f / nrm;     // fold sqrt(d)/norm into pre-quantize scale
    s2[tid] = nrm * 0.0625f;   // fold norm/sqrt(d) into output scale
  }
  // s1/s2 visibility covered by the post-staging sync inside the jt loop

  // ---- mm1: y = (x @ R^T) * s1 ; quantize -> u8 indices ----
  for (int jt = 0; jt < 4; ++jt) {
    const int j0 = jt * 64;
    __syncthreads();  // prior users of rs done
    #pragma unroll
    for (int it = 0; it < 16; ++it) {
      int f = it * 256 + tid;
      int jj = f >> 6;
      int c4 = f & 63;
      float4 v = ((const float4*)(R + (long)(j0 + jj) * 256))[c4];
      *(float4*)&rs[jj][c4 * 4] = v;
    }
    __syncthreads();

    float acc[4][4] = {};
    #pragma unroll 2
    for (int k = 0; k < 256; k += 4) {
      float4 a[4], b[4];
      #pragma unroll
      for (int r = 0; r < 4; ++r) a[r] = *(const float4*)&xs[ty + 16 * r][k];
      #pragma unroll
      for (int c = 0; c < 4; ++c) b[c] = *(const float4*)&rs[tx + 16 * c][k];
      #pragma unroll
      for (int r = 0; r < 4; ++r)
        #pragma unroll
        for (int c = 0; c < 4; ++c)
          acc[r][c] += a[r].x * b[c].x + a[r].y * b[c].y +
                       a[r].z * b[c].z + a[r].w * b[c].w;
    }

    #pragma unroll
    for (int r = 0; r < 4; ++r) {
      const int i = ty + 16 * r;
      const float s = s1[i];
      #pragma unroll
      for (int c = 0; c < 4; ++c) {
        float y = acc[r][c] * s;
        int id = 0;
        #pragma unroll
        for (int t = 0; t < 15; ++t) id += (y > mid[t]) ? 1 : 0;
        ys[i][j0 + tx + 16 * c] = (unsigned char)id;
      }
    }
  }

  __syncthreads();  // all ys written
  // ---- dequant: xs <- codebook[idx] (raw codebook value; /16 folded in s2) ----
  #pragma unroll 4
  for (int i = 0; i < MT; ++i) {
    xs[i][tid] = cbs[ys[i][tid]];
  }

  // ---- mm2: out = (c @ R) * s2 ----
  for (int jt = 0; jt < 4; ++jt) {
    const int j0 = jt * 64;
    __syncthreads();  // dequant writes + prior rs users done
    #pragma unroll
    for (int it = 0; it < 16; ++it) {
      int k = it * 16 + ty;   // 16 k-rows per iter, 4 rows per wave
      int jc = tx * 4;
      float4 v = *(const float4*)(R + (long)k * 256 + j0 + jc);
      rs[jc + 0][k] = v.x;
      rs[jc + 1][k] = v.y;
      rs[jc + 2][k] = v.z;
      rs[jc + 3][k] = v.w;
    }
    __syncthreads();

    float acc[4][4] = {};
    #pragma unroll 2
    for (int k = 0; k < 256; k += 4) {
      float4 a[4], b[4];
      #pragma unroll
      for (int r = 0; r < 4; ++r) a[r] = *(const float4*)&xs[ty + 16 * r][k];
      #pragma unroll
      for (int c = 0; c < 4; ++c) b[c] = *(const float4*)&rs[tx + 16 * c][k];
      #pragma unroll
      for (int r = 0; r < 4; ++r)
        #pragma unroll
        for (int c = 0; c < 4; ++c)
          acc[r][c] += a[r].x * b[c].x + a[r].y * b[c].y +
                       a[r].z * b[c].z + a[r].w * b[c].w;
    }

    #pragma unroll
    for (int r = 0; r < 4; ++r) {
      const int i = ty + 16 * r;
      const float s = s2[i];
      #pragma unroll
      for (int c = 0; c < 4; ++c)
        OUT[(row0 + i) * 256 + j0 + tx + 16 * c] = acc[r][c] * s;
    }
  }
}

extern "C" void kernel_launch(void* const* d_in, const int* in_sizes, int n_in,
                              void* d_out, int out_size, void* d_ws, size_t ws_size,
                              hipStream_t stream) {
  const float* X = (const float*)d_in[0];
  const float* R = (const float*)d_in[1];
  const float* CB = (const float*)d_in[2];
  float* OUT = (float*)d_out;
  const int nrows = in_sizes[0] / 256;        // 16384
  const int nblocks = nrows / MT;             // 256
  tq_kernel<<<nblocks, 256, 0, stream>>>(X, R, CB, OUT);
}

// Round 4
// 36.008 us; speedup vs baseline: 3.0333x; 3.0333x over previous
//
#include <hip/hip_runtime.h>

typedef _Float16 f16;
typedef _Float16 f16x4 __attribute__((ext_vector_type(4)));
typedef _Float16 f16x8 __attribute__((ext_vector_type(8)));
typedef float f32x16 __attribute__((ext_vector_type(16)));
typedef float f32x4 __attribute__((ext_vector_type(4)));

#define APITCH 264   // f16; 528 B row pitch, 16B aligned
#define B1PITCH 40   // f16; 80 B row pitch, 16B aligned
#define B2PITCH 264  // f16; mm2 [k][n] tile pitch

__global__ __launch_bounds__(256, 1) void tq_main(
    const float* __restrict__ X, const float* __restrict__ R,
    const float* __restrict__ CB, float* __restrict__ OUT) {
  __shared__ f16 A1h[64][APITCH];
  __shared__ f16 A1l[64][APITCH];
  __shared__ f16 Qs[64][APITCH];
  __shared__ f32x4 Braw[2624];  // 41984 B; mm1: B1h|B1l (40960 B); mm2: B2h (16896 B)
  __shared__ float pn[4][64];
  __shared__ float s1s[64];
  __shared__ float s2s[64];

  f16 (*B1h)[B1PITCH] = (f16(*)[B1PITCH])Braw;
  f16 (*B1l)[B1PITCH] = (f16(*)[B1PITCH])((char*)Braw + 20480);
  f16 (*B2h)[B2PITCH] = (f16(*)[B2PITCH])Braw;

  const int tid = threadIdx.x;
  const int lane = tid & 63;
  const int wv = tid >> 6;
  const int lrow = lane & 31;
  const int kg = lane >> 5;
  const long row0 = (long)blockIdx.x * 64;

  // ---- codebook: scaled midpoints + packed f16 values ----
  float cbf[16];
  #pragma unroll
  for (int i = 0; i < 16; ++i) cbf[i] = CB[i];
  float M[15];
  #pragma unroll
  for (int t = 0; t < 15; ++t) M[t] = 65536.0f * (0.5f * (cbf[t] + cbf[t + 1]));
  unsigned int cpk[8];
  #pragma unroll
  for (int i = 0; i < 8; ++i) {
    f16 lo16 = (f16)cbf[2 * i];
    f16 hi16 = (f16)cbf[2 * i + 1];
    unsigned short lb = __builtin_bit_cast(unsigned short, lo16);
    unsigned short hb = __builtin_bit_cast(unsigned short, hi16);
    cpk[i] = ((unsigned int)hb << 16) | (unsigned int)lb;
  }

  // ---- load x (64 floats/thread), norms ----
  const int xrow = tid >> 2, xq = tid & 3;
  const float* xp = X + (row0 + xrow) * 256 + xq * 64;
  float xa[64];
  #pragma unroll
  for (int i = 0; i < 16; ++i) {
    f32x4 v = ((const f32x4*)xp)[i];
    xa[4 * i] = v.x; xa[4 * i + 1] = v.y; xa[4 * i + 2] = v.z; xa[4 * i + 3] = v.w;
  }
  float ss = 0.f;
  #pragma unroll
  for (int i = 0; i < 64; ++i) ss += xa[i] * xa[i];
  pn[xq][xrow] = ss;
  __syncthreads();
  if (tid < 64) {
    float s = pn[0][tid] + pn[1][tid] + pn[2][tid] + pn[3][tid];
    float nrm = fmaxf(sqrtf(s), 1e-8f);
    s1s[tid] = 4096.0f / nrm;   // 2^12/norm : A scale (y_raw = 65536*y_scaled)
    s2s[tid] = nrm * 0.0625f;   // norm/16   : output scale
  }
  __syncthreads();

  // ---- split A = x*s1 into f16 hi/lo -> LDS ----
  {
    float s1f = s1s[xrow];
    #pragma unroll
    for (int c8 = 0; c8 < 8; ++c8) {
      f16x8 h, l;
      #pragma unroll
      for (int j = 0; j < 8; ++j) {
        float a = xa[c8 * 8 + j] * s1f;
        f16 hh = (f16)a;
        h[j] = hh;
        l[j] = (f16)(a - (float)hh);
      }
      *(f16x8*)&A1h[xrow][xq * 64 + c8 * 8] = h;
      *(f16x8*)&A1l[xrow][xq * 64 + c8 * 8] = l;
    }
  }

  // ---- prefetch mm1 panel 0 (raw fp32 R rows, coalesced) ----
  // chunk c = q*256+tid: n = c>>3, k4 = (c&7)*4  -> covers [256 n][32 k]
  f32x4 pf[8];
  #pragma unroll
  for (int q = 0; q < 8; ++q) {
    int c = q * 256 + tid;
    pf[q] = *(const f32x4*)&R[(long)(c >> 3) * 256 + ((c & 7) * 4)];
  }

  f32x16 zv;
  #pragma unroll
  for (int i = 0; i < 16; ++i) zv[i] = 0.0f;
  f32x16 acc[2][2];
  acc[0][0] = zv; acc[0][1] = zv; acc[1][0] = zv; acc[1][1] = zv;

  // ---- mm1: y_raw = (4096/nrm * x) @ (256*R)^T, 4-term f16 split ----
  for (int kp = 0; kp < 8; ++kp) {
    __syncthreads();  // prev compute done with B1 (and A writes visible at kp=0)
    #pragma unroll
    for (int q = 0; q < 8; ++q) {
      int c = q * 256 + tid;
      int n = c >> 3, k4 = (c & 7) * 4;
      f16x4 h, l;
      #pragma unroll
      for (int j = 0; j < 4; ++j) {
        float sv = pf[q][j] * 256.0f;
        f16 hh = (f16)sv;
        h[j] = hh;
        l[j] = (f16)(sv - (float)hh);
      }
      *(f16x4*)&B1h[n][k4] = h;
      *(f16x4*)&B1l[n][k4] = l;
    }
    __syncthreads();
    if (kp < 7) {
      #pragma unroll
      for (int q = 0; q < 8; ++q) {
        int c = q * 256 + tid;
        pf[q] = *(const f32x4*)&R[(long)(c >> 3) * 256 + (kp + 1) * 32 + ((c & 7) * 4)];
      }
    }
    #pragma unroll
    for (int ks = 0; ks < 2; ++ks) {
      const int k0 = kp * 32 + ks * 16 + kg * 8;
      const int lk = ks * 16 + kg * 8;
      f16x8 ah[2], al[2], bhf[2], blf[2];
      #pragma unroll
      for (int m = 0; m < 2; ++m) {
        ah[m] = *(const f16x8*)&A1h[32 * m + lrow][k0];
        al[m] = *(const f16x8*)&A1l[32 * m + lrow][k0];
      }
      #pragma unroll
      for (int n = 0; n < 2; ++n) {
        int col = 64 * wv + 32 * n + lrow;
        bhf[n] = *(const f16x8*)&B1h[col][lk];
        blf[n] = *(const f16x8*)&B1l[col][lk];
      }
      #pragma unroll
      for (int m = 0; m < 2; ++m)
        #pragma unroll
        for (int n = 0; n < 2; ++n) {
          acc[m][n] = __builtin_amdgcn_mfma_f32_32x32x16_f16(ah[m], bhf[n], acc[m][n], 0, 0, 0);
          acc[m][n] = __builtin_amdgcn_mfma_f32_32x32x16_f16(al[m], bhf[n], acc[m][n], 0, 0, 0);
          acc[m][n] = __builtin_amdgcn_mfma_f32_32x32x16_f16(ah[m], blf[n], acc[m][n], 0, 0, 0);
          acc[m][n] = __builtin_amdgcn_mfma_f32_32x32x16_f16(al[m], blf[n], acc[m][n], 0, 0, 0);
        }
    }
  }

  // ---- prefetch mm2 panel 0: chunk c: k = c>>6, n4 = (c&63)*4 ----
  #pragma unroll
  for (int q = 0; q < 8; ++q) {
    int c = q * 256 + tid;
    pf[q] = *(const f32x4*)&R[(long)(c >> 6) * 256 + ((c & 63) * 4)];
  }

  // ---- quantize: branchless binary tree on y_raw vs 65536*midpoints ----
  // id = 8*b3 + 4*b2 + 2*b1 + b0; level-t midpoint index = 8b3+4b2+2b1 truncated.
  #pragma unroll
  for (int m = 0; m < 2; ++m)
    #pragma unroll
    for (int n = 0; n < 2; ++n)
      #pragma unroll
      for (int r = 0; r < 16; ++r) {
        float y = acc[m][n][r];
        int row = 32 * m + 4 * kg + (r & 3) + 8 * (r >> 2);
        int kk = 64 * wv + 32 * n + lrow;
        bool b3 = y > M[7];
        float m2 = b3 ? M[11] : M[3];                       // M[8b3+3]
        bool b2 = y > m2;
        float m1 = b3 ? (b2 ? M[13] : M[9])                 // M[8b3+4b2+1]
                      : (b2 ? M[5] : M[1]);
        bool b1 = y > m1;
        float m0 = b1 ? (b3 ? (b2 ? M[14] : M[10]) : (b2 ? M[6] : M[2]))   // M[8b3+4b2+2b1]
                      : (b3 ? (b2 ? M[12] : M[8]) : (b2 ? M[4] : M[0]));
        bool b0 = y > m0;
        unsigned int pp = b3 ? (b2 ? (b1 ? cpk[7] : cpk[6]) : (b1 ? cpk[5] : cpk[4]))
                             : (b2 ? (b1 ? cpk[3] : cpk[2]) : (b1 ? cpk[1] : cpk[0]));
        unsigned short qb = (unsigned short)(b0 ? (pp >> 16) : (pp & 0xFFFFu));
        Qs[row][kk] = __builtin_bit_cast(f16, qb);
      }
  __syncthreads();  // Qs complete; last mm1 compute done with B1 (aliased by B2)

  f32x16 acc2[2][2];
  acc2[0][0] = zv; acc2[0][1] = zv; acc2[1][0] = zv; acc2[1][1] = zv;

  // ---- mm2: out_raw = Q @ R (B staged [k][n], f16 single-term) ----
  for (int kp = 0; kp < 8; ++kp) {
    if (kp) __syncthreads();
    #pragma unroll
    for (int q = 0; q < 8; ++q) {
      int c = q * 256 + tid;
      int k = c >> 6, n4 = (c & 63) * 4;
      f16x4 h;
      #pragma unroll
      for (int j = 0; j < 4; ++j) h[j] = (f16)pf[q][j];
      *(f16x4*)&B2h[k][n4] = h;
    }
    __syncthreads();
    if (kp < 7) {
      #pragma unroll
      for (int q = 0; q < 8; ++q) {
        int c = q * 256 + tid;
        pf[q] = *(const f32x4*)&R[(long)((kp + 1) * 32 + (c >> 6)) * 256 + ((c & 63) * 4)];
      }
    }
    #pragma unroll
    for (int ks = 0; ks < 2; ++ks) {
      const int k0 = kp * 32 + ks * 16 + kg * 8;
      const int lk = ks * 16 + kg * 8;
      f16x8 qa[2], bb[2];
      #pragma unroll
      for (int m = 0; m < 2; ++m) qa[m] = *(const f16x8*)&Qs[32 * m + lrow][k0];
      #pragma unroll
      for (int n = 0; n < 2; ++n) {
        int colg = 64 * wv + 32 * n + lrow;
        #pragma unroll
        for (int j = 0; j < 8; ++j) bb[n][j] = B2h[lk + j][colg];
      }
      #pragma unroll
      for (int m = 0; m < 2; ++m)
        #pragma unroll
        for (int n = 0; n < 2; ++n)
          acc2[m][n] = __builtin_amdgcn_mfma_f32_32x32x16_f16(qa[m], bb[n], acc2[m][n], 0, 0, 0);
    }
  }

  // ---- epilogue: out = acc2 * (norm/16) ----
  #pragma unroll
  for (int m = 0; m < 2; ++m)
    #pragma unroll
    for (int n = 0; n < 2; ++n)
      #pragma unroll
      for (int r = 0; r < 16; ++r) {
        int row = 32 * m + 4 * kg + (r & 3) + 8 * (r >> 2);
        int col = 64 * wv + 32 * n + lrow;
        OUT[(row0 + row) * 256 + col] = acc2[m][n][r] * s2s[row];
      }
}

extern "C" void kernel_launch(void* const* d_in, const int* in_sizes, int n_in,
                              void* d_out, int out_size, void* d_ws, size_t ws_size,
                              hipStream_t stream) {
  const float* X = (const float*)d_in[0];
  const float* R = (const float*)d_in[1];
  const float* CB = (const float*)d_in[2];
  float* OUT = (float*)d_out;
  const int nrows = in_sizes[0] / 256;  // 16384
  const int nblocks = nrows / 64;       // 256
  tq_main<<<nblocks, 256, 0, stream>>>(X, R, CB, OUT);
}

// Round 5
// 28.128 us; speedup vs baseline: 3.8830x; 1.2801x over previous
//
#include <hip/hip_runtime.h>

typedef _Float16 f16;
typedef _Float16 f16x4 __attribute__((ext_vector_type(4)));
typedef _Float16 f16x8 __attribute__((ext_vector_type(8)));
typedef float f32x16 __attribute__((ext_vector_type(16)));
typedef float f32x4 __attribute__((ext_vector_type(4)));

#define APITCH 264  // f16 units; 528 B pitch, 16B aligned

// ============================================================================
// prep: build fragment-major f16 B-operands in ws (one fragment = 64 lanes x
// 8 f16 = 1024 B, contiguous -> wave loads it with one global_load_dwordx4).
// frag f = g*16 + ks16 (g: 32-col group, ks16: 16-k chunk); elem (l, j):
//   W1h/W1l: f16 hi/lo of 256*R[32g + (l&31)][16*ks16 + 8*(l>>5) + j]   (mm1 B)
//   W2h    : f16 of        R[16*ks16 + 8*(l>>5) + j][32g + (l&31)]      (mm2 B)
// ============================================================================
__global__ void prep_kernel(const float* __restrict__ R, f16* __restrict__ ws) {
  f16* W1h = ws;
  f16* W1l = ws + 65536;
  f16* W2h = ws + 131072;
  const int f = blockIdx.x;      // 0..127
  const int g = f >> 4, ks16 = f & 15;
  const int t = threadIdx.x;     // 0..511 ; t = l*8 + j
  const int l = t >> 3, j = t & 7;
  const int col = 32 * g + (l & 31);
  const int k = 16 * ks16 + 8 * (l >> 5) + j;
  float v1 = R[col * 256 + k] * 256.0f;
  f16 h = (f16)v1;
  f16 lo = (f16)(v1 - (float)h);
  W1h[f * 512 + t] = h;
  W1l[f * 512 + t] = lo;
  W2h[f * 512 + t] = (f16)R[k * 256 + col];
}

// ============================================================================
// main: 512 blocks x 512 threads (8 waves), 32 rows/block, wave tile 32x32.
// No barriers inside either k-loop (B comes from L2-resident ws fragments).
// ============================================================================
__global__ __launch_bounds__(512, 4) void tq_main(
    const float* __restrict__ X, const float* __restrict__ CB,
    const f16* __restrict__ ws, float* __restrict__ OUT) {
  __shared__ f16 A1h[32][APITCH];   // re-used as Qs after mm1
  __shared__ f16 A1l[32][APITCH];
  __shared__ float pn[16][32];
  __shared__ float s1s[32], s2s[32];

  const int tid = threadIdx.x;
  const int lane = tid & 63;
  const int wv = tid >> 6;      // 0..7 = 32-col group g
  const int lrow = lane & 31;
  const int kg = lane >> 5;
  const long row0 = (long)blockIdx.x * 32;

  const f16* W1h = ws;
  const f16* W1l = ws + 65536;
  const f16* W2h = ws + 131072;

  // ---- load x (16 floats/thread: row=tid>>4, 16-col chunk=tid&15) ----
  const int r = tid >> 4, q = tid & 15;
  const float* xp = X + (row0 + r) * 256 + q * 16;
  float xa[16];
  #pragma unroll
  for (int i = 0; i < 4; ++i) {
    f32x4 v = ((const f32x4*)xp)[i];
    xa[4 * i] = v.x; xa[4 * i + 1] = v.y; xa[4 * i + 2] = v.z; xa[4 * i + 3] = v.w;
  }
  float ss = 0.f;
  #pragma unroll
  for (int i = 0; i < 16; ++i) ss += xa[i] * xa[i];
  pn[q][r] = ss;
  __syncthreads();
  if (tid < 32) {
    float s = 0.f;
    #pragma unroll
    for (int i = 0; i < 16; ++i) s += pn[i][tid];
    float nrm = fmaxf(sqrtf(s), 1e-8f);
    s1s[tid] = 4096.0f / nrm;   // y_raw = 65536 * y_scaled
    s2s[tid] = nrm * 0.0625f;
  }
  __syncthreads();

  // ---- split A = x * s1 into f16 hi/lo -> LDS ----
  {
    float s1f = s1s[r];
    #pragma unroll
    for (int c8 = 0; c8 < 2; ++c8) {
      f16x8 h, l;
      #pragma unroll
      for (int j = 0; j < 8; ++j) {
        float a = xa[c8 * 8 + j] * s1f;
        f16 hh = (f16)a;
        h[j] = hh;
        l[j] = (f16)(a - (float)hh);
      }
      *(f16x8*)&A1h[r][q * 16 + c8 * 8] = h;
      *(f16x8*)&A1l[r][q * 16 + c8 * 8] = l;
    }
  }
  __syncthreads();

  // ---- mm1: barrier-free k-loop, dual accumulator chains ----
  const int fb = wv * 16;                 // this wave's fragment base
  const int lofs = lane * 8;              // f16 offset within fragment
  f16x8 bh = *(const f16x8*)(W1h + fb * 512 + lofs);
  f16x8 bl = *(const f16x8*)(W1l + fb * 512 + lofs);
  f32x16 zv;
  #pragma unroll
  for (int i = 0; i < 16; ++i) zv[i] = 0.0f;
  f32x16 accH = zv, accL = zv;
  #pragma unroll 4
  for (int ks = 0; ks < 16; ++ks) {
    f16x8 cbh = bh, cbl = bl;
    if (ks < 15) {
      bh = *(const f16x8*)(W1h + (fb + ks + 1) * 512 + lofs);
      bl = *(const f16x8*)(W1l + (fb + ks + 1) * 512 + lofs);
    }
    const int k0 = ks * 16 + kg * 8;
    f16x8 ah = *(const f16x8*)&A1h[lrow][k0];
    f16x8 al = *(const f16x8*)&A1l[lrow][k0];
    accH = __builtin_amdgcn_mfma_f32_32x32x16_f16(ah, cbh, accH, 0, 0, 0);
    accL = __builtin_amdgcn_mfma_f32_32x32x16_f16(al, cbh, accL, 0, 0, 0);
    accH = __builtin_amdgcn_mfma_f32_32x32x16_f16(ah, cbl, accH, 0, 0, 0);
    accL = __builtin_amdgcn_mfma_f32_32x32x16_f16(al, cbl, accL, 0, 0, 0);
  }
  f32x16 acc;
  #pragma unroll
  for (int i = 0; i < 16; ++i) acc[i] = accH[i] + accL[i];

  __syncthreads();  // all waves done reading A1h/A1l before Qs overwrite

  // ---- codebook (loaded late to keep mm1 register pressure low) ----
  float cbf[16];
  #pragma unroll
  for (int i = 0; i < 16; ++i) cbf[i] = CB[i];
  float M[15];
  #pragma unroll
  for (int t = 0; t < 15; ++t) M[t] = 65536.0f * (0.5f * (cbf[t] + cbf[t + 1]));
  unsigned int cpk[8];
  #pragma unroll
  for (int i = 0; i < 8; ++i) {
    unsigned short lb = __builtin_bit_cast(unsigned short, (f16)cbf[2 * i]);
    unsigned short hb = __builtin_bit_cast(unsigned short, (f16)cbf[2 * i + 1]);
    cpk[i] = ((unsigned int)hb << 16) | (unsigned int)lb;
  }

  // ---- quantize -> Qs (aliases A1h): Qs[xrow][ycoord] ----
  f16 (*Qs)[APITCH] = A1h;
  #pragma unroll
  for (int rr = 0; rr < 16; ++rr) {
    float y = acc[rr];
    int row = 4 * kg + (rr & 3) + 8 * (rr >> 2);
    int kk = 32 * wv + lrow;
    bool b3 = y > M[7];
    float m2 = b3 ? M[11] : M[3];
    bool b2 = y > m2;
    float m1 = b3 ? (b2 ? M[13] : M[9]) : (b2 ? M[5] : M[1]);
    bool b1 = y > m1;
    float m0 = b1 ? (b3 ? (b2 ? M[14] : M[10]) : (b2 ? M[6] : M[2]))
                  : (b3 ? (b2 ? M[12] : M[8]) : (b2 ? M[4] : M[0]));
    bool b0 = y > m0;
    unsigned int pp = b3 ? (b2 ? (b1 ? cpk[7] : cpk[6]) : (b1 ? cpk[5] : cpk[4]))
                         : (b2 ? (b1 ? cpk[3] : cpk[2]) : (b1 ? cpk[1] : cpk[0]));
    unsigned short qb = (unsigned short)(b0 ? (pp >> 16) : (pp & 0xFFFFu));
    Qs[row][kk] = __builtin_bit_cast(f16, qb);
  }
  __syncthreads();

  // ---- mm2: barrier-free k-loop ----
  f16x8 b2 = *(const f16x8*)(W2h + fb * 512 + lofs);
  f32x16 acc2 = zv;
  #pragma unroll 4
  for (int ks = 0; ks < 16; ++ks) {
    f16x8 cb2 = b2;
    if (ks < 15) b2 = *(const f16x8*)(W2h + (fb + ks + 1) * 512 + lofs);
    f16x8 qa = *(const f16x8*)&Qs[lrow][ks * 16 + kg * 8];
    acc2 = __builtin_amdgcn_mfma_f32_32x32x16_f16(qa, cb2, acc2, 0, 0, 0);
  }

  // ---- epilogue ----
  #pragma unroll
  for (int rr = 0; rr < 16; ++rr) {
    int row = 4 * kg + (rr & 3) + 8 * (rr >> 2);
    int col = 32 * wv + lrow;
    OUT[(row0 + row) * 256 + col] = acc2[rr] * s2s[row];
  }
}

// ============================================================================
// fallback (round-4 kernel, passed at 36 us) if ws is too small
// ============================================================================
#define FB_APITCH 264
#define FB_B1PITCH 40
#define FB_B2PITCH 264

__global__ __launch_bounds__(256, 1) void tq_main_fb(
    const float* __restrict__ X, const float* __restrict__ R,
    const float* __restrict__ CB, float* __restrict__ OUT) {
  __shared__ f16 A1h[64][FB_APITCH];
  __shared__ f16 A1l[64][FB_APITCH];
  __shared__ f16 Qs[64][FB_APITCH];
  __shared__ f32x4 Braw[2624];
  __shared__ float pn[4][64];
  __shared__ float s1s[64];
  __shared__ float s2s[64];

  f16 (*B1h)[FB_B1PITCH] = (f16(*)[FB_B1PITCH])Braw;
  f16 (*B1l)[FB_B1PITCH] = (f16(*)[FB_B1PITCH])((char*)Braw + 20480);
  f16 (*B2h)[FB_B2PITCH] = (f16(*)[FB_B2PITCH])Braw;

  const int tid = threadIdx.x;
  const int lane = tid & 63;
  const int wv = tid >> 6;
  const int lrow = lane & 31;
  const int kg = lane >> 5;
  const long row0 = (long)blockIdx.x * 64;

  float cbf[16];
  #pragma unroll
  for (int i = 0; i < 16; ++i) cbf[i] = CB[i];
  float M[15];
  #pragma unroll
  for (int t = 0; t < 15; ++t) M[t] = 65536.0f * (0.5f * (cbf[t] + cbf[t + 1]));
  unsigned int cpk[8];
  #pragma unroll
  for (int i = 0; i < 8; ++i) {
    unsigned short lb = __builtin_bit_cast(unsigned short, (f16)cbf[2 * i]);
    unsigned short hb = __builtin_bit_cast(unsigned short, (f16)cbf[2 * i + 1]);
    cpk[i] = ((unsigned int)hb << 16) | (unsigned int)lb;
  }

  const int xrow = tid >> 2, xq = tid & 3;
  const float* xp = X + (row0 + xrow) * 256 + xq * 64;
  float xa[64];
  #pragma unroll
  for (int i = 0; i < 16; ++i) {
    f32x4 v = ((const f32x4*)xp)[i];
    xa[4 * i] = v.x; xa[4 * i + 1] = v.y; xa[4 * i + 2] = v.z; xa[4 * i + 3] = v.w;
  }
  float ss = 0.f;
  #pragma unroll
  for (int i = 0; i < 64; ++i) ss += xa[i] * xa[i];
  pn[xq][xrow] = ss;
  __syncthreads();
  if (tid < 64) {
    float s = pn[0][tid] + pn[1][tid] + pn[2][tid] + pn[3][tid];
    float nrm = fmaxf(sqrtf(s), 1e-8f);
    s1s[tid] = 4096.0f / nrm;
    s2s[tid] = nrm * 0.0625f;
  }
  __syncthreads();

  {
    float s1f = s1s[xrow];
    #pragma unroll
    for (int c8 = 0; c8 < 8; ++c8) {
      f16x8 h, l;
      #pragma unroll
      for (int j = 0; j < 8; ++j) {
        float a = xa[c8 * 8 + j] * s1f;
        f16 hh = (f16)a;
        h[j] = hh;
        l[j] = (f16)(a - (float)hh);
      }
      *(f16x8*)&A1h[xrow][xq * 64 + c8 * 8] = h;
      *(f16x8*)&A1l[xrow][xq * 64 + c8 * 8] = l;
    }
  }

  f32x4 pf[8];
  #pragma unroll
  for (int q = 0; q < 8; ++q) {
    int c = q * 256 + tid;
    pf[q] = *(const f32x4*)&R[(long)(c >> 3) * 256 + ((c & 7) * 4)];
  }

  f32x16 zv;
  #pragma unroll
  for (int i = 0; i < 16; ++i) zv[i] = 0.0f;
  f32x16 acc[2][2];
  acc[0][0] = zv; acc[0][1] = zv; acc[1][0] = zv; acc[1][1] = zv;

  for (int kp = 0; kp < 8; ++kp) {
    __syncthreads();
    #pragma unroll
    for (int q = 0; q < 8; ++q) {
      int c = q * 256 + tid;
      int n = c >> 3, k4 = (c & 7) * 4;
      f16x4 h, l;
      #pragma unroll
      for (int j = 0; j < 4; ++j) {
        float sv = pf[q][j] * 256.0f;
        f16 hh = (f16)sv;
        h[j] = hh;
        l[j] = (f16)(sv - (float)hh);
      }
      *(f16x4*)&B1h[n][k4] = h;
      *(f16x4*)&B1l[n][k4] = l;
    }
    __syncthreads();
    if (kp < 7) {
      #pragma unroll
      for (int q = 0; q < 8; ++q) {
        int c = q * 256 + tid;
        pf[q] = *(const f32x4*)&R[(long)(c >> 3) * 256 + (kp + 1) * 32 + ((c & 7) * 4)];
      }
    }
    #pragma unroll
    for (int ks = 0; ks < 2; ++ks) {
      const int k0 = kp * 32 + ks * 16 + kg * 8;
      const int lk = ks * 16 + kg * 8;
      f16x8 ah[2], al[2], bhf[2], blf[2];
      #pragma unroll
      for (int m = 0; m < 2; ++m) {
        ah[m] = *(const f16x8*)&A1h[32 * m + lrow][k0];
        al[m] = *(const f16x8*)&A1l[32 * m + lrow][k0];
      }
      #pragma unroll
      for (int n = 0; n < 2; ++n) {
        int col = 64 * wv + 32 * n + lrow;
        bhf[n] = *(const f16x8*)&B1h[col][lk];
        blf[n] = *(const f16x8*)&B1l[col][lk];
      }
      #pragma unroll
      for (int m = 0; m < 2; ++m)
        #pragma unroll
        for (int n = 0; n < 2; ++n) {
          acc[m][n] = __builtin_amdgcn_mfma_f32_32x32x16_f16(ah[m], bhf[n], acc[m][n], 0, 0, 0);
          acc[m][n] = __builtin_amdgcn_mfma_f32_32x32x16_f16(al[m], bhf[n], acc[m][n], 0, 0, 0);
          acc[m][n] = __builtin_amdgcn_mfma_f32_32x32x16_f16(ah[m], blf[n], acc[m][n], 0, 0, 0);
          acc[m][n] = __builtin_amdgcn_mfma_f32_32x32x16_f16(al[m], blf[n], acc[m][n], 0, 0, 0);
        }
    }
  }

  #pragma unroll
  for (int q = 0; q < 8; ++q) {
    int c = q * 256 + tid;
    pf[q] = *(const f32x4*)&R[(long)(c >> 6) * 256 + ((c & 63) * 4)];
  }

  #pragma unroll
  for (int m = 0; m < 2; ++m)
    #pragma unroll
    for (int n = 0; n < 2; ++n)
      #pragma unroll
      for (int rr = 0; rr < 16; ++rr) {
        float y = acc[m][n][rr];
        int row = 32 * m + 4 * kg + (rr & 3) + 8 * (rr >> 2);
        int kk = 64 * wv + 32 * n + lrow;
        bool b3 = y > M[7];
        float m2 = b3 ? M[11] : M[3];
        bool b2 = y > m2;
        float m1 = b3 ? (b2 ? M[13] : M[9]) : (b2 ? M[5] : M[1]);
        bool b1 = y > m1;
        float m0 = b1 ? (b3 ? (b2 ? M[14] : M[10]) : (b2 ? M[6] : M[2]))
                      : (b3 ? (b2 ? M[12] : M[8]) : (b2 ? M[4] : M[0]));
        bool b0 = y > m0;
        unsigned int pp = b3 ? (b2 ? (b1 ? cpk[7] : cpk[6]) : (b1 ? cpk[5] : cpk[4]))
                             : (b2 ? (b1 ? cpk[3] : cpk[2]) : (b1 ? cpk[1] : cpk[0]));
        unsigned short qb = (unsigned short)(b0 ? (pp >> 16) : (pp & 0xFFFFu));
        Qs[row][kk] = __builtin_bit_cast(f16, qb);
      }
  __syncthreads();

  f32x16 acc2[2][2];
  acc2[0][0] = zv; acc2[0][1] = zv; acc2[1][0] = zv; acc2[1][1] = zv;

  for (int kp = 0; kp < 8; ++kp) {
    if (kp) __syncthreads();
    #pragma unroll
    for (int q = 0; q < 8; ++q) {
      int c = q * 256 + tid;
      int k = c >> 6, n4 = (c & 63) * 4;
      f16x4 h;
      #pragma unroll
      for (int j = 0; j < 4; ++j) h[j] = (f16)pf[q][j];
      *(f16x4*)&B2h[k][n4] = h;
    }
    __syncthreads();
    if (kp < 7) {
      #pragma unroll
      for (int q = 0; q < 8; ++q) {
        int c = q * 256 + tid;
        pf[q] = *(const f32x4*)&R[(long)((kp + 1) * 32 + (c >> 6)) * 256 + ((c & 63) * 4)];
      }
    }
    #pragma unroll
    for (int ks = 0; ks < 2; ++ks) {
      const int k0 = kp * 32 + ks * 16 + kg * 8;
      const int lk = ks * 16 + kg * 8;
      f16x8 qa[2], bb[2];
      #pragma unroll
      for (int m = 0; m < 2; ++m) qa[m] = *(const f16x8*)&Qs[32 * m + lrow][k0];
      #pragma unroll
      for (int n = 0; n < 2; ++n) {
        int colg = 64 * wv + 32 * n + lrow;
        #pragma unroll
        for (int j = 0; j < 8; ++j) bb[n][j] = B2h[lk + j][colg];
      }
      #pragma unroll
      for (int m = 0; m < 2; ++m)
        #pragma unroll
        for (int n = 0; n < 2; ++n)
          acc2[m][n] = __builtin_amdgcn_mfma_f32_32x32x16_f16(qa[m], bb[n], acc2[m][n], 0, 0, 0);
    }
  }

  #pragma unroll
  for (int m = 0; m < 2; ++m)
    #pragma unroll
    for (int n = 0; n < 2; ++n)
      #pragma unroll
      for (int rr = 0; rr < 16; ++rr) {
        int row = 32 * m + 4 * kg + (rr & 3) + 8 * (rr >> 2);
        int col = 64 * wv + 32 * n + lrow;
        OUT[(row0 + row) * 256 + col] = acc2[m][n][rr] * s2s[row];
      }
}

extern "C" void kernel_launch(void* const* d_in, const int* in_sizes, int n_in,
                              void* d_out, int out_size, void* d_ws, size_t ws_size,
                              hipStream_t stream) {
  const float* X = (const float*)d_in[0];
  const float* R = (const float*)d_in[1];
  const float* CB = (const float*)d_in[2];
  float* OUT = (float*)d_out;
  const int nrows = in_sizes[0] / 256;  // 16384

  if (ws_size >= 3u * 65536u * sizeof(f16)) {
    f16* ws = (f16*)d_ws;
    prep_kernel<<<128, 512, 0, stream>>>(R, ws);
    tq_main<<<nrows / 32, 512, 0, stream>>>(X, CB, ws, OUT);
  } else {
    tq_main_fb<<<nrows / 64, 256, 0, stream>>>(X, R, CB, OUT);
  }
}

// Round 6
// 27.132 us; speedup vs baseline: 4.0256x; 1.0367x over previous
//
#include <hip/hip_runtime.h>

typedef _Float16 f16;
typedef _Float16 f16x4 __attribute__((ext_vector_type(4)));
typedef _Float16 f16x8 __attribute__((ext_vector_type(8)));
typedef float f32x16 __attribute__((ext_vector_type(16)));
typedef float f32x4 __attribute__((ext_vector_type(4)));

#define APITCH 264       // f16 units; 528 B pitch
#define WREG 67584       // f16 units per ws region: 65536 + 2048 pad (OOB prefetch)

// ============================================================================
// prep: build fragment-major f16 B-operands in ws.
// Fragment spec (f = g*16 + ks16; elem index l*8+j, l=0..63, j=0..7):
//   W1h/W1l[f*512 + l*8 + j] = f16 hi/lo of 256*R[32g + (l&31)][16*ks16 + 8*(l>>5) + j]
//   W2h    [f*512 + l*8 + j] = f16 of        R[16*ks16 + 8*(l>>5) + j][32g + (l&31)]
// 8 blocks; block g stages R rows 32g..32g+31 in LDS (coalesced), then:
//   - W1 frags {g*16 + 0..15}    : LDS row-major reads (b128, uniform banks)
//   - W2 frags {g'*16+2g+e, all g'}: LDS column gather (2 lanes/bank = free)
// ============================================================================
__global__ __launch_bounds__(1024) void prep_kernel(const float* __restrict__ R,
                                                    f16* __restrict__ ws) {
  __shared__ float Lrs[32][260];
  const int g = blockIdx.x;   // 0..7
  const int t = threadIdx.x;  // 0..1023
  f16* W1h = ws;
  f16* W1l = ws + WREG;
  f16* W2h = ws + 2 * WREG;

  #pragma unroll
  for (int it = 0; it < 2; ++it) {
    int c = it * 1024 + t;            // 0..2047
    int row = c >> 6, c4 = (c & 63) * 4;
    f32x4 v = *(const f32x4*)&R[(long)(32 * g + row) * 256 + c4];
    *(f32x4*)&Lrs[row][c4] = v;
  }
  __syncthreads();

  // ---- W1h/W1l: chunk c = t: f_loc = c>>6, l = c&63 ----
  {
    int f_loc = t >> 6, l = t & 63;
    int k0 = 16 * f_loc + 8 * (l >> 5);
    const float* src = &Lrs[l & 31][k0];
    f16x8 h, lo;
    #pragma unroll
    for (int j = 0; j < 8; ++j) {
      float v = src[j] * 256.0f;
      f16 hh = (f16)v;
      h[j] = hh;
      lo[j] = (f16)(v - (float)hh);
    }
    long o = (long)(g * 16 + f_loc) * 512 + l * 8;
    *(f16x8*)(W1h + o) = h;
    *(f16x8*)(W1l + o) = lo;
  }

  // ---- W2h: chunk c = t: g' = c>>7, e = (c>>6)&1, l = c&63 ----
  {
    int gp = t >> 7, e = (t >> 6) & 1, l = t & 63;
    int lr0 = 16 * e + 8 * (l >> 5);    // local R-row base (k - 32g)
    int col = 32 * gp + (l & 31);
    f16x8 h;
    #pragma unroll
    for (int j = 0; j < 8; ++j) h[j] = (f16)Lrs[lr0 + j][col];
    long o = (long)(gp * 16 + 2 * g + e) * 512 + l * 8;
    *(f16x8*)(W2h + o) = h;
  }
}

// ============================================================================
// main: 512 blocks x 512 threads, 32 rows/block, wave tile 32x32.
// Barrier-free k-loops; depth-2 (mm1) / depth-4 (mm2) fragment prefetch.
// ============================================================================
__global__ __launch_bounds__(512, 4) void tq_main(
    const float* __restrict__ X, const float* __restrict__ CB,
    const f16* __restrict__ ws, float* __restrict__ OUT) {
  __shared__ f16 A1h[32][APITCH];   // aliased as Qs after mm1
  __shared__ f16 A1l[32][APITCH];
  __shared__ float s2s[32];

  const int tid = threadIdx.x;
  const int lane = tid & 63;
  const int wv = tid >> 6;       // 0..7 = 32-col group
  const int lrow = lane & 31;
  const int kg = lane >> 5;
  const long row0 = (long)blockIdx.x * 32;

  const f16* W1h = ws;
  const f16* W1l = ws + WREG;
  const f16* W2h = ws + 2 * WREG;

  // ---- load x (16 floats/thread), wave-local norm via shfl (no barriers) ----
  const int r = tid >> 4, q = tid & 15;
  const float* xp = X + (row0 + r) * 256 + q * 16;
  float xa[16];
  #pragma unroll
  for (int i = 0; i < 4; ++i) {
    f32x4 v = ((const f32x4*)xp)[i];
    xa[4 * i] = v.x; xa[4 * i + 1] = v.y; xa[4 * i + 2] = v.z; xa[4 * i + 3] = v.w;
  }
  float ss = 0.f;
  #pragma unroll
  for (int i = 0; i < 16; ++i) ss += xa[i] * xa[i];
  ss += __shfl_xor(ss, 8, 16);
  ss += __shfl_xor(ss, 4, 16);
  ss += __shfl_xor(ss, 2, 16);
  ss += __shfl_xor(ss, 1, 16);
  float nrm = fmaxf(sqrtf(ss), 1e-8f);
  float s1f = 4096.0f / nrm;         // y_raw = 65536 * y_scaled
  if (q == 0) s2s[r] = nrm * 0.0625f;

  // ---- split A = x*s1 into f16 hi/lo -> LDS ----
  #pragma unroll
  for (int c8 = 0; c8 < 2; ++c8) {
    f16x8 h, l;
    #pragma unroll
    for (int j = 0; j < 8; ++j) {
      float a = xa[c8 * 8 + j] * s1f;
      f16 hh = (f16)a;
      h[j] = hh;
      l[j] = (f16)(a - (float)hh);
    }
    *(f16x8*)&A1h[r][q * 16 + c8 * 8] = h;
    *(f16x8*)&A1l[r][q * 16 + c8 * 8] = l;
  }
  __syncthreads();

  // ---- mm1: depth-2 prefetch, dual acc chains, no barriers ----
  const f16* W1hp = W1h + (long)(wv * 16) * 512 + lane * 8;
  const f16* W1lp = W1l + (long)(wv * 16) * 512 + lane * 8;
  f16x8 bh0 = *(const f16x8*)(W1hp);
  f16x8 bl0 = *(const f16x8*)(W1lp);
  f16x8 bh1 = *(const f16x8*)(W1hp + 512);
  f16x8 bl1 = *(const f16x8*)(W1lp + 512);

  f32x16 zv;
  #pragma unroll
  for (int i = 0; i < 16; ++i) zv[i] = 0.0f;
  f32x16 accH = zv, accL = zv;

  #pragma unroll
  for (int ks = 0; ks < 16; ks += 2) {
    {
      const int k0 = ks * 16 + kg * 8;
      f16x8 ah = *(const f16x8*)&A1h[lrow][k0];
      f16x8 al = *(const f16x8*)&A1l[lrow][k0];
      accH = __builtin_amdgcn_mfma_f32_32x32x16_f16(ah, bh0, accH, 0, 0, 0);
      accL = __builtin_amdgcn_mfma_f32_32x32x16_f16(al, bh0, accL, 0, 0, 0);
      accH = __builtin_amdgcn_mfma_f32_32x32x16_f16(ah, bl0, accH, 0, 0, 0);
      accL = __builtin_amdgcn_mfma_f32_32x32x16_f16(al, bl0, accL, 0, 0, 0);
      bh0 = *(const f16x8*)(W1hp + (ks + 2) * 512);   // ks=14 -> pad region
      bl0 = *(const f16x8*)(W1lp + (ks + 2) * 512);
    }
    {
      const int k0 = (ks + 1) * 16 + kg * 8;
      f16x8 ah = *(const f16x8*)&A1h[lrow][k0];
      f16x8 al = *(const f16x8*)&A1l[lrow][k0];
      accH = __builtin_amdgcn_mfma_f32_32x32x16_f16(ah, bh1, accH, 0, 0, 0);
      accL = __builtin_amdgcn_mfma_f32_32x32x16_f16(al, bh1, accL, 0, 0, 0);
      accH = __builtin_amdgcn_mfma_f32_32x32x16_f16(ah, bl1, accH, 0, 0, 0);
      accL = __builtin_amdgcn_mfma_f32_32x32x16_f16(al, bl1, accL, 0, 0, 0);
      bh1 = *(const f16x8*)(W1hp + (ks + 3) * 512);
      bl1 = *(const f16x8*)(W1lp + (ks + 3) * 512);
    }
  }
  f32x16 acc;
  #pragma unroll
  for (int i = 0; i < 16; ++i) acc[i] = accH[i] + accL[i];

  // ---- issue mm2 preloads (latency hides under quantize) ----
  const f16* W2p = W2h + (long)(wv * 16) * 512 + lane * 8;
  f16x8 c0 = *(const f16x8*)(W2p);
  f16x8 c1 = *(const f16x8*)(W2p + 512);
  f16x8 c2 = *(const f16x8*)(W2p + 1024);
  f16x8 c3 = *(const f16x8*)(W2p + 1536);

  __syncthreads();   // all waves done reading A1h/A1l (Qs aliases A1h)

  // ---- codebook ----
  float cbf[16];
  #pragma unroll
  for (int i = 0; i < 16; ++i) cbf[i] = CB[i];
  float M[15];
  #pragma unroll
  for (int t = 0; t < 15; ++t) M[t] = 65536.0f * (0.5f * (cbf[t] + cbf[t + 1]));
  unsigned int cpk[8];
  #pragma unroll
  for (int i = 0; i < 8; ++i) {
    unsigned short lb = __builtin_bit_cast(unsigned short, (f16)cbf[2 * i]);
    unsigned short hb = __builtin_bit_cast(unsigned short, (f16)cbf[2 * i + 1]);
    cpk[i] = ((unsigned int)hb << 16) | (unsigned int)lb;
  }

  // ---- quantize -> Qs (aliases A1h): id = 8b3+4b2+2b1+b0 ----
  f16 (*Qs)[APITCH] = A1h;
  #pragma unroll
  for (int rr = 0; rr < 16; ++rr) {
    float y = acc[rr];
    int row = 4 * kg + (rr & 3) + 8 * (rr >> 2);
    int kk = 32 * wv + lrow;
    bool b3 = y > M[7];
    float m2 = b3 ? M[11] : M[3];
    bool b2 = y > m2;
    float m1 = b3 ? (b2 ? M[13] : M[9]) : (b2 ? M[5] : M[1]);
    bool b1 = y > m1;
    float m0 = b1 ? (b3 ? (b2 ? M[14] : M[10]) : (b2 ? M[6] : M[2]))
                  : (b3 ? (b2 ? M[12] : M[8]) : (b2 ? M[4] : M[0]));
    bool b0 = y > m0;
    unsigned int pp = b3 ? (b2 ? (b1 ? cpk[7] : cpk[6]) : (b1 ? cpk[5] : cpk[4]))
                         : (b2 ? (b1 ? cpk[3] : cpk[2]) : (b1 ? cpk[1] : cpk[0]));
    unsigned short qb = (unsigned short)(b0 ? (pp >> 16) : (pp & 0xFFFFu));
    Qs[row][kk] = __builtin_bit_cast(f16, qb);
  }
  __syncthreads();

  // ---- mm2: depth-4 rotation, 2 acc chains, no barriers ----
  f32x16 acc2a = zv, acc2b = zv;
  #pragma unroll
  for (int ks = 0; ks < 16; ks += 4) {
    {
      f16x8 qa = *(const f16x8*)&Qs[lrow][ks * 16 + kg * 8];
      acc2a = __builtin_amdgcn_mfma_f32_32x32x16_f16(qa, c0, acc2a, 0, 0, 0);
      c0 = *(const f16x8*)(W2p + (ks + 4) * 512);     // ks=12 -> pad region
    }
    {
      f16x8 qa = *(const f16x8*)&Qs[lrow][(ks + 1) * 16 + kg * 8];
      acc2b = __builtin_amdgcn_mfma_f32_32x32x16_f16(qa, c1, acc2b, 0, 0, 0);
      c1 = *(const f16x8*)(W2p + (ks + 5) * 512);
    }
    {
      f16x8 qa = *(const f16x8*)&Qs[lrow][(ks + 2) * 16 + kg * 8];
      acc2a = __builtin_amdgcn_mfma_f32_32x32x16_f16(qa, c2, acc2a, 0, 0, 0);
      c2 = *(const f16x8*)(W2p + (ks + 6) * 512);
    }
    {
      f16x8 qa = *(const f16x8*)&Qs[lrow][(ks + 3) * 16 + kg * 8];
      acc2b = __builtin_amdgcn_mfma_f32_32x32x16_f16(qa, c3, acc2b, 0, 0, 0);
      c3 = *(const f16x8*)(W2p + (ks + 7) * 512);
    }
  }

  // ---- epilogue ----
  #pragma unroll
  for (int rr = 0; rr < 16; ++rr) {
    int row = 4 * kg + (rr & 3) + 8 * (rr >> 2);
    int col = 32 * wv + lrow;
    OUT[(row0 + row) * 256 + col] = (acc2a[rr] + acc2b[rr]) * s2s[row];
  }
}

// ============================================================================
// fallback (round-4 kernel, passed at 36 us) if ws is too small
// ============================================================================
#define FB_APITCH 264
#define FB_B1PITCH 40
#define FB_B2PITCH 264

__global__ __launch_bounds__(256, 1) void tq_main_fb(
    const float* __restrict__ X, const float* __restrict__ R,
    const float* __restrict__ CB, float* __restrict__ OUT) {
  __shared__ f16 A1h[64][FB_APITCH];
  __shared__ f16 A1l[64][FB_APITCH];
  __shared__ f16 Qs[64][FB_APITCH];
  __shared__ f32x4 Braw[2624];
  __shared__ float pn[4][64];
  __shared__ float s1s[64];
  __shared__ float s2s[64];

  f16 (*B1h)[FB_B1PITCH] = (f16(*)[FB_B1PITCH])Braw;
  f16 (*B1l)[FB_B1PITCH] = (f16(*)[FB_B1PITCH])((char*)Braw + 20480);
  f16 (*B2h)[FB_B2PITCH] = (f16(*)[FB_B2PITCH])Braw;

  const int tid = threadIdx.x;
  const int lane = tid & 63;
  const int wv = tid >> 6;
  const int lrow = lane & 31;
  const int kg = lane >> 5;
  const long row0 = (long)blockIdx.x * 64;

  float cbf[16];
  #pragma unroll
  for (int i = 0; i < 16; ++i) cbf[i] = CB[i];
  float M[15];
  #pragma unroll
  for (int t = 0; t < 15; ++t) M[t] = 65536.0f * (0.5f * (cbf[t] + cbf[t + 1]));
  unsigned int cpk[8];
  #pragma unroll
  for (int i = 0; i < 8; ++i) {
    unsigned short lb = __builtin_bit_cast(unsigned short, (f16)cbf[2 * i]);
    unsigned short hb = __builtin_bit_cast(unsigned short, (f16)cbf[2 * i + 1]);
    cpk[i] = ((unsigned int)hb << 16) | (unsigned int)lb;
  }

  const int xrow = tid >> 2, xq = tid & 3;
  const float* xp = X + (row0 + xrow) * 256 + xq * 64;
  float xa[64];
  #pragma unroll
  for (int i = 0; i < 16; ++i) {
    f32x4 v = ((const f32x4*)xp)[i];
    xa[4 * i] = v.x; xa[4 * i + 1] = v.y; xa[4 * i + 2] = v.z; xa[4 * i + 3] = v.w;
  }
  float ss = 0.f;
  #pragma unroll
  for (int i = 0; i < 64; ++i) ss += xa[i] * xa[i];
  pn[xq][xrow] = ss;
  __syncthreads();
  if (tid < 64) {
    float s = pn[0][tid] + pn[1][tid] + pn[2][tid] + pn[3][tid];
    float nrm = fmaxf(sqrtf(s), 1e-8f);
    s1s[tid] = 4096.0f / nrm;
    s2s[tid] = nrm * 0.0625f;
  }
  __syncthreads();

  {
    float s1f = s1s[xrow];
    #pragma unroll
    for (int c8 = 0; c8 < 8; ++c8) {
      f16x8 h, l;
      #pragma unroll
      for (int j = 0; j < 8; ++j) {
        float a = xa[c8 * 8 + j] * s1f;
        f16 hh = (f16)a;
        h[j] = hh;
        l[j] = (f16)(a - (float)hh);
      }
      *(f16x8*)&A1h[xrow][xq * 64 + c8 * 8] = h;
      *(f16x8*)&A1l[xrow][xq * 64 + c8 * 8] = l;
    }
  }

  f32x4 pf[8];
  #pragma unroll
  for (int q = 0; q < 8; ++q) {
    int c = q * 256 + tid;
    pf[q] = *(const f32x4*)&R[(long)(c >> 3) * 256 + ((c & 7) * 4)];
  }

  f32x16 zv;
  #pragma unroll
  for (int i = 0; i < 16; ++i) zv[i] = 0.0f;
  f32x16 acc[2][2];
  acc[0][0] = zv; acc[0][1] = zv; acc[1][0] = zv; acc[1][1] = zv;

  for (int kp = 0; kp < 8; ++kp) {
    __syncthreads();
    #pragma unroll
    for (int q = 0; q < 8; ++q) {
      int c = q * 256 + tid;
      int n = c >> 3, k4 = (c & 7) * 4;
      f16x4 h, l;
      #pragma unroll
      for (int j = 0; j < 4; ++j) {
        float sv = pf[q][j] * 256.0f;
        f16 hh = (f16)sv;
        h[j] = hh;
        l[j] = (f16)(sv - (float)hh);
      }
      *(f16x4*)&B1h[n][k4] = h;
      *(f16x4*)&B1l[n][k4] = l;
    }
    __syncthreads();
    if (kp < 7) {
      #pragma unroll
      for (int q = 0; q < 8; ++q) {
        int c = q * 256 + tid;
        pf[q] = *(const f32x4*)&R[(long)(c >> 3) * 256 + (kp + 1) * 32 + ((c & 7) * 4)];
      }
    }
    #pragma unroll
    for (int ks = 0; ks < 2; ++ks) {
      const int k0 = kp * 32 + ks * 16 + kg * 8;
      const int lk = ks * 16 + kg * 8;
      f16x8 ah[2], al[2], bhf[2], blf[2];
      #pragma unroll
      for (int m = 0; m < 2; ++m) {
        ah[m] = *(const f16x8*)&A1h[32 * m + lrow][k0];
        al[m] = *(const f16x8*)&A1l[32 * m + lrow][k0];
      }
      #pragma unroll
      for (int n = 0; n < 2; ++n) {
        int col = 64 * wv + 32 * n + lrow;
        bhf[n] = *(const f16x8*)&B1h[col][lk];
        blf[n] = *(const f16x8*)&B1l[col][lk];
      }
      #pragma unroll
      for (int m = 0; m < 2; ++m)
        #pragma unroll
        for (int n = 0; n < 2; ++n) {
          acc[m][n] = __builtin_amdgcn_mfma_f32_32x32x16_f16(ah[m], bhf[n], acc[m][n], 0, 0, 0);
          acc[m][n] = __builtin_amdgcn_mfma_f32_32x32x16_f16(al[m], bhf[n], acc[m][n], 0, 0, 0);
          acc[m][n] = __builtin_amdgcn_mfma_f32_32x32x16_f16(ah[m], blf[n], acc[m][n], 0, 0, 0);
          acc[m][n] = __builtin_amdgcn_mfma_f32_32x32x16_f16(al[m], blf[n], acc[m][n], 0, 0, 0);
        }
    }
  }

  #pragma unroll
  for (int q = 0; q < 8; ++q) {
    int c = q * 256 + tid;
    pf[q] = *(const f32x4*)&R[(long)(c >> 6) * 256 + ((c & 63) * 4)];
  }

  #pragma unroll
  for (int m = 0; m < 2; ++m)
    #pragma unroll
    for (int n = 0; n < 2; ++n)
      #pragma unroll
      for (int rr = 0; rr < 16; ++rr) {
        float y = acc[m][n][rr];
        int row = 32 * m + 4 * kg + (rr & 3) + 8 * (rr >> 2);
        int kk = 64 * wv + 32 * n + lrow;
        bool b3 = y > M[7];
        float m2 = b3 ? M[11] : M[3];
        bool b2 = y > m2;
        float m1 = b3 ? (b2 ? M[13] : M[9]) : (b2 ? M[5] : M[1]);
        bool b1 = y > m1;
        float m0 = b1 ? (b3 ? (b2 ? M[14] : M[10]) : (b2 ? M[6] : M[2]))
                      : (b3 ? (b2 ? M[12] : M[8]) : (b2 ? M[4] : M[0]));
        bool b0 = y > m0;
        unsigned int pp = b3 ? (b2 ? (b1 ? cpk[7] : cpk[6]) : (b1 ? cpk[5] : cpk[4]))
                             : (b2 ? (b1 ? cpk[3] : cpk[2]) : (b1 ? cpk[1] : cpk[0]));
        unsigned short qb = (unsigned short)(b0 ? (pp >> 16) : (pp & 0xFFFFu));
        Qs[row][kk] = __builtin_bit_cast(f16, qb);
      }
  __syncthreads();

  f32x16 acc2[2][2];
  acc2[0][0] = zv; acc2[0][1] = zv; acc2[1][0] = zv; acc2[1][1] = zv;

  for (int kp = 0; kp < 8; ++kp) {
    if (kp) __syncthreads();
    #pragma unroll
    for (int q = 0; q < 8; ++q) {
      int c = q * 256 + tid;
      int k = c >> 6, n4 = (c & 63) * 4;
      f16x4 h;
      #pragma unroll
      for (int j = 0; j < 4; ++j) h[j] = (f16)pf[q][j];
      *(f16x4*)&B2h[k][n4] = h;
    }
    __syncthreads();
    if (kp < 7) {
      #pragma unroll
      for (int q = 0; q < 8; ++q) {
        int c = q * 256 + tid;
        pf[q] = *(const f32x4*)&R[(long)((kp + 1) * 32 + (c >> 6)) * 256 + ((c & 63) * 4)];
      }
    }
    #pragma unroll
    for (int ks = 0; ks < 2; ++ks) {
      const int k0 = kp * 32 + ks * 16 + kg * 8;
      const int lk = ks * 16 + kg * 8;
      f16x8 qa[2], bb[2];
      #pragma unroll
      for (int m = 0; m < 2; ++m) qa[m] = *(const f16x8*)&Qs[32 * m + lrow][k0];
      #pragma unroll
      for (int n = 0; n < 2; ++n) {
        int colg = 64 * wv + 32 * n + lrow;
        #pragma unroll
        for (int j = 0; j < 8; ++j) bb[n][j] = B2h[lk + j][colg];
      }
      #pragma unroll
      for (int m = 0; m < 2; ++m)
        #pragma unroll
        for (int n = 0; n < 2; ++n)
          acc2[m][n] = __builtin_amdgcn_mfma_f32_32x32x16_f16(qa[m], bb[n], acc2[m][n], 0, 0, 0);
    }
  }

  #pragma unroll
  for (int m = 0; m < 2; ++m)
    #pragma unroll
    for (int n = 0; n < 2; ++n)
      #pragma unroll
      for (int rr = 0; rr < 16; ++rr) {
        int row = 32 * m + 4 * kg + (rr & 3) + 8 * (rr >> 2);
        int col = 64 * wv + 32 * n + lrow;
        OUT[(row0 + row) * 256 + col] = acc2[m][n][rr] * s2s[row];
      }
}

extern "C" void kernel_launch(void* const* d_in, const int* in_sizes, int n_in,
                              void* d_out, int out_size, void* d_ws, size_t ws_size,
                              hipStream_t stream) {
  const float* X = (const float*)d_in[0];
  const float* R = (const float*)d_in[1];
  const float* CB = (const float*)d_in[2];
  float* OUT = (float*)d_out;
  const int nrows = in_sizes[0] / 256;  // 16384

  if (ws_size >= (size_t)3 * WREG * sizeof(f16)) {
    f16* ws = (f16*)d_ws;
    prep_kernel<<<8, 1024, 0, stream>>>(R, ws);
    tq_main<<<nrows / 32, 512, 0, stream>>>(X, CB, ws, OUT);
  } else {
    tq_main_fb<<<nrows / 64, 256, 0, stream>>>(X, R, CB, OUT);
  }
}